// Round 4
// baseline (59.001 us; speedup 1.0000x reference)
//
#include <hip/hip_runtime.h>
#include <hip/hip_bf16.h>

// DataTerm layer: out[b,h,w,:] = {u,v} - ALPHA * dataTerm * {dI1_dy, dI1_dx}
// where dataTerm = bilinear_sample(I1, normalized-coords-misused-as-pixels) - I2.
// Reference quirks preserved:
//  - (dy,dx) bound as (grad_x,grad_y): u uses the ROW diff, v the COL diff.
//  - warp normalizes coords to [-1,1] then samples them as raw pixels, so all
//    bilinear corners land in the 3x3 top-left patch -> preload 9 uniform
//    values, select with cndmask (round-2 win: removed gather latency chain).
// Round-3 changes:
//  - 8 pixels/thread: 2x VMEM ILP per wave, half the index math.
//  - non-temporal output stores (via clang ext_vector — HIP_vector_type is a
//    struct and the builtin rejects it): output (67 MB, never re-read) stops
//    evicting the 134 MB of inputs from the 256 MB LLC across timed replays.

#define ALPHA 0.1f

constexpr int B = 32, H = 512, W = 512;

typedef float floatx4 __attribute__((ext_vector_type(4)));

__global__ __launch_bounds__(256) void dataterm_kernel(
    const float* __restrict__ I1,
    const float* __restrict__ I2,
    const float* __restrict__ flow,
    float* __restrict__ out)
{
    // 128 blocks per batch image; b is wave-uniform -> s_loads for the patch.
    int b   = blockIdx.x >> 7;
    int idx = ((blockIdx.x & 127) << 8) | threadIdx.x;  // 8-pixel group in image
    int w8  = (idx & (W / 8 - 1)) * 8;                  // 64 groups/row
    int h   = idx >> 6;

    const float* I1b = I1 + (size_t)b * (H * W);
    // Block-uniform 3x3 corner patch (all bilinear corners live here).
    float S00 = I1b[0],     S01 = I1b[1],         S02 = I1b[2];
    float S10 = I1b[W],     S11 = I1b[W + 1],     S12 = I1b[W + 2];
    float S20 = I1b[2 * W], S21 = I1b[2 * W + 1], S22 = I1b[2 * W + 2];

    size_t rowoff = (size_t)(b * H + h) * W + w8;

    float4 i1v0 = *(const float4*)(I1 + rowoff);
    float4 i1v1 = *(const float4*)(I1 + rowoff + 4);
    float4 i2v0 = *(const float4*)(I2 + rowoff);
    float4 i2v1 = *(const float4*)(I2 + rowoff + 4);
    bool has_dn = (h < H - 1);
    float4 dn0 = make_float4(0.f, 0.f, 0.f, 0.f), dn1 = dn0;
    if (has_dn) {
        dn0 = *(const float4*)(I1 + rowoff + W);
        dn1 = *(const float4*)(I1 + rowoff + W + 4);
    }
    float i1r8 = (w8 + 8 < W) ? I1[rowoff + 8] : 0.0f;

    const float* fp = flow + 2 * rowoff;
    float4 f0 = *(const float4*)(fp);       // u0 v0 u1 v1
    float4 f1 = *(const float4*)(fp + 4);   // u2 v2 u3 v3
    float4 f2 = *(const float4*)(fp + 8);   // u4 v4 u5 v5
    float4 f3 = *(const float4*)(fp + 12);  // u6 v6 u7 v7

    float uarr[8] = { f0.x, f0.z, f1.x, f1.z, f2.x, f2.z, f3.x, f3.z };
    float varr[8] = { f0.y, f0.w, f1.y, f1.w, f2.y, f2.w, f3.y, f3.w };
    float i1a[9]  = { i1v0.x, i1v0.y, i1v0.z, i1v0.w,
                      i1v1.x, i1v1.y, i1v1.z, i1v1.w, i1r8 };
    float i1d[8]  = { dn0.x, dn0.y, dn0.z, dn0.w, dn1.x, dn1.y, dn1.z, dn1.w };
    float i2a[8]  = { i2v0.x, i2v0.y, i2v0.z, i2v0.w,
                      i2v1.x, i2v1.y, i2v1.z, i2v1.w };

    const float sx = 2.0f / (W - 1.0f);
    const float sy = 2.0f / (H - 1.0f);

    float on[16];
#pragma unroll
    for (int j = 0; j < 8; ++j) {
        int w = w8 + j;
        float u = uarr[j], v = varr[j];
        float x = ((float)w + 0.5f * u) * sx - 1.0f;
        float y = ((float)h + 0.5f * v) * sy - 1.0f;
        float x0f = floorf(x), y0f = floorf(y);
        float x1f = x0f + 1.0f, y1f = y0f + 1.0f;
        x0f = fminf(fmaxf(x0f, 0.0f), W - 1.0f);
        x1f = fminf(fmaxf(x1f, 0.0f), W - 1.0f);
        y0f = fminf(fmaxf(y0f, 0.0f), H - 1.0f);
        y1f = fminf(fmaxf(y1f, 0.0f), H - 1.0f);
        int x0i = (int)x0f, x1i = (int)x1f;   // in {0,1} / {0,1,2}
        int y0i = (int)y0f, y1i = (int)y1f;

        // Select corner values from the preloaded 3x3 patch (pure VALU).
        float r0 = (x0i == 0) ? S00 : S01;
        float r1 = (x0i == 0) ? S10 : S11;
        float r2 = (x0i == 0) ? S20 : S21;
        float q0 = (x1i == 0) ? S00 : ((x1i == 1) ? S01 : S02);
        float q1 = (x1i == 0) ? S10 : ((x1i == 1) ? S11 : S12);
        float q2 = (x1i == 0) ? S20 : ((x1i == 1) ? S21 : S22);
        float Ia  = (y0i == 0) ? r0 : r1;
        float Ibv = (y1i == 0) ? r0 : ((y1i == 1) ? r1 : r2);
        float Ic  = (y0i == 0) ? q0 : q1;
        float Id  = (y1i == 0) ? q0 : ((y1i == 1) ? q1 : q2);

        float wa = (x1f - x) * (y1f - y);
        float wb = (x1f - x) * (y - y0f);
        float wc = (x - x0f) * (y1f - y);
        float wd = (x - x0f) * (y - y0f);
        float warped = wa * Ia + wb * Ibv + wc * Ic + wd * Id;
        float dt = warped - i2a[j];
        float gdy = has_dn ? (i1d[j] - i1a[j]) : 0.0f;          // row diff -> u
        float gdx = (w < W - 1) ? (i1a[j + 1] - i1a[j]) : 0.0f; // col diff -> v
        on[2 * j]     = u - ALPHA * dt * gdy;
        on[2 * j + 1] = v - ALPHA * dt * gdx;
    }

    float* op = out + 2 * rowoff;
    floatx4 o0 = { on[0],  on[1],  on[2],  on[3]  };
    floatx4 o1 = { on[4],  on[5],  on[6],  on[7]  };
    floatx4 o2 = { on[8],  on[9],  on[10], on[11] };
    floatx4 o3 = { on[12], on[13], on[14], on[15] };
    __builtin_nontemporal_store(o0, (floatx4*)(op));
    __builtin_nontemporal_store(o1, (floatx4*)(op + 4));
    __builtin_nontemporal_store(o2, (floatx4*)(op + 8));
    __builtin_nontemporal_store(o3, (floatx4*)(op + 12));
}

extern "C" void kernel_launch(void* const* d_in, const int* in_sizes, int n_in,
                              void* d_out, int out_size, void* d_ws, size_t ws_size,
                              hipStream_t stream) {
    const float* I1   = (const float*)d_in[0];
    const float* I2   = (const float*)d_in[1];
    const float* flow = (const float*)d_in[2];
    float* out = (float*)d_out;

    int total_threads = B * H * (W / 8);           // 1,048,576
    int block = 256;
    int grid = total_threads / block;              // 4096
    dataterm_kernel<<<grid, block, 0, stream>>>(I1, I2, flow, out);
}

// Round 5
// 46.152 us; speedup vs baseline: 1.2784x; 1.2784x over previous
//
#include <hip/hip_runtime.h>
#include <hip/hip_bf16.h>

// DataTerm layer: out[b,h,w,:] = {u,v} - ALPHA * dataTerm * {dI1_dy, dI1_dx}
// where dataTerm = bilinear_sample(I1, normalized-coords-misused-as-pixels) - I2.
// Reference quirks preserved:
//  - (dy,dx) bound as (grad_x,grad_y): u uses the ROW diff, v the COL diff.
//  - warp normalizes coords to [-1,1] then samples them as raw pixels, so all
//    bilinear corners land in the 3x3 top-left patch -> preload 9 uniform
//    values, select with cndmask (round-2 win: removed gather latency chain).
// Round-5: 8 pixels/thread (ILP), PLAIN cached stores. Round-4 post-mortem:
// __builtin_nontemporal_store bypassed the LLC (WRITE_SIZE 66->117 MB,
// dur 53->87 us profiled) — NT stores were the regression, reverted.

#define ALPHA 0.1f

constexpr int B = 32, H = 512, W = 512;

__global__ __launch_bounds__(256) void dataterm_kernel(
    const float* __restrict__ I1,
    const float* __restrict__ I2,
    const float* __restrict__ flow,
    float* __restrict__ out)
{
    // 128 blocks per batch image; b is wave-uniform -> s_loads for the patch.
    int b   = blockIdx.x >> 7;
    int idx = ((blockIdx.x & 127) << 8) | threadIdx.x;  // 8-pixel group in image
    int w8  = (idx & (W / 8 - 1)) * 8;                  // 64 groups/row
    int h   = idx >> 6;

    const float* I1b = I1 + (size_t)b * (H * W);
    // Block-uniform 3x3 corner patch (all bilinear corners live here).
    float S00 = I1b[0],     S01 = I1b[1],         S02 = I1b[2];
    float S10 = I1b[W],     S11 = I1b[W + 1],     S12 = I1b[W + 2];
    float S20 = I1b[2 * W], S21 = I1b[2 * W + 1], S22 = I1b[2 * W + 2];

    size_t rowoff = (size_t)(b * H + h) * W + w8;

    float4 i1v0 = *(const float4*)(I1 + rowoff);
    float4 i1v1 = *(const float4*)(I1 + rowoff + 4);
    float4 i2v0 = *(const float4*)(I2 + rowoff);
    float4 i2v1 = *(const float4*)(I2 + rowoff + 4);
    bool has_dn = (h < H - 1);
    float4 dn0 = make_float4(0.f, 0.f, 0.f, 0.f), dn1 = dn0;
    if (has_dn) {
        dn0 = *(const float4*)(I1 + rowoff + W);
        dn1 = *(const float4*)(I1 + rowoff + W + 4);
    }
    float i1r8 = (w8 + 8 < W) ? I1[rowoff + 8] : 0.0f;

    const float* fp = flow + 2 * rowoff;
    float4 f0 = *(const float4*)(fp);       // u0 v0 u1 v1
    float4 f1 = *(const float4*)(fp + 4);   // u2 v2 u3 v3
    float4 f2 = *(const float4*)(fp + 8);   // u4 v4 u5 v5
    float4 f3 = *(const float4*)(fp + 12);  // u6 v6 u7 v7

    float uarr[8] = { f0.x, f0.z, f1.x, f1.z, f2.x, f2.z, f3.x, f3.z };
    float varr[8] = { f0.y, f0.w, f1.y, f1.w, f2.y, f2.w, f3.y, f3.w };
    float i1a[9]  = { i1v0.x, i1v0.y, i1v0.z, i1v0.w,
                      i1v1.x, i1v1.y, i1v1.z, i1v1.w, i1r8 };
    float i1d[8]  = { dn0.x, dn0.y, dn0.z, dn0.w, dn1.x, dn1.y, dn1.z, dn1.w };
    float i2a[8]  = { i2v0.x, i2v0.y, i2v0.z, i2v0.w,
                      i2v1.x, i2v1.y, i2v1.z, i2v1.w };

    const float sx = 2.0f / (W - 1.0f);
    const float sy = 2.0f / (H - 1.0f);

    float on[16];
#pragma unroll
    for (int j = 0; j < 8; ++j) {
        int w = w8 + j;
        float u = uarr[j], v = varr[j];
        float x = ((float)w + 0.5f * u) * sx - 1.0f;
        float y = ((float)h + 0.5f * v) * sy - 1.0f;
        float x0f = floorf(x), y0f = floorf(y);
        float x1f = x0f + 1.0f, y1f = y0f + 1.0f;
        x0f = fminf(fmaxf(x0f, 0.0f), W - 1.0f);
        x1f = fminf(fmaxf(x1f, 0.0f), W - 1.0f);
        y0f = fminf(fmaxf(y0f, 0.0f), H - 1.0f);
        y1f = fminf(fmaxf(y1f, 0.0f), H - 1.0f);
        int x0i = (int)x0f, x1i = (int)x1f;   // in {0,1} / {0,1,2}
        int y0i = (int)y0f, y1i = (int)y1f;

        // Select corner values from the preloaded 3x3 patch (pure VALU).
        float r0 = (x0i == 0) ? S00 : S01;
        float r1 = (x0i == 0) ? S10 : S11;
        float r2 = (x0i == 0) ? S20 : S21;
        float q0 = (x1i == 0) ? S00 : ((x1i == 1) ? S01 : S02);
        float q1 = (x1i == 0) ? S10 : ((x1i == 1) ? S11 : S12);
        float q2 = (x1i == 0) ? S20 : ((x1i == 1) ? S21 : S22);
        float Ia  = (y0i == 0) ? r0 : r1;
        float Ibv = (y1i == 0) ? r0 : ((y1i == 1) ? r1 : r2);
        float Ic  = (y0i == 0) ? q0 : q1;
        float Id  = (y1i == 0) ? q0 : ((y1i == 1) ? q1 : q2);

        float wa = (x1f - x) * (y1f - y);
        float wb = (x1f - x) * (y - y0f);
        float wc = (x - x0f) * (y1f - y);
        float wd = (x - x0f) * (y - y0f);
        float warped = wa * Ia + wb * Ibv + wc * Ic + wd * Id;
        float dt = warped - i2a[j];
        float gdy = has_dn ? (i1d[j] - i1a[j]) : 0.0f;          // row diff -> u
        float gdx = (w < W - 1) ? (i1a[j + 1] - i1a[j]) : 0.0f; // col diff -> v
        on[2 * j]     = u - ALPHA * dt * gdy;
        on[2 * j + 1] = v - ALPHA * dt * gdx;
    }

    float* op = out + 2 * rowoff;
    *(float4*)(op)      = make_float4(on[0],  on[1],  on[2],  on[3]);
    *(float4*)(op + 4)  = make_float4(on[4],  on[5],  on[6],  on[7]);
    *(float4*)(op + 8)  = make_float4(on[8],  on[9],  on[10], on[11]);
    *(float4*)(op + 12) = make_float4(on[12], on[13], on[14], on[15]);
}

extern "C" void kernel_launch(void* const* d_in, const int* in_sizes, int n_in,
                              void* d_out, int out_size, void* d_ws, size_t ws_size,
                              hipStream_t stream) {
    const float* I1   = (const float*)d_in[0];
    const float* I2   = (const float*)d_in[1];
    const float* flow = (const float*)d_in[2];
    float* out = (float*)d_out;

    int total_threads = B * H * (W / 8);           // 1,048,576
    int block = 256;
    int grid = total_threads / block;              // 4096
    dataterm_kernel<<<grid, block, 0, stream>>>(I1, I2, flow, out);
}

// Round 6
// 38.305 us; speedup vs baseline: 1.5403x; 1.2048x over previous
//
#include <hip/hip_runtime.h>
#include <hip/hip_bf16.h>

// DataTerm layer: out[b,h,w,:] = {u,v} - ALPHA * dataTerm * {dI1_dy, dI1_dx}
// where dataTerm = bilinear_sample(I1, normalized-coords-misused-as-pixels) - I2.
// Reference quirks preserved:
//  - (dy,dx) bound as (grad_x,grad_y): u uses the ROW diff, v the COL diff.
//  - warp normalizes coords to [-1,1] then samples them as raw pixels, so all
//    bilinear corners land in the 3x3 top-left patch -> preload 9 uniform
//    values, select with cndmask (round-2 win).
// Round-6: 2 pixels/thread.
//  - out per thread = ONE float4, unit stride across lanes -> every store
//    instruction writes a fully-contiguous 1KB line. Round-5 post-mortem:
//    8px/thread stores (16B per lane at 64B stride) caused partial-line HBM
//    write amplification (WRITE_SIZE 66->109MB). This layout makes
//    amplification impossible by construction.
//  - NT store on the full-line pattern: output (67MB, never re-read) skips
//    LLC allocation -> the 134MB of inputs stay LLC-resident across replays
//    -> steady-state FETCH_SIZE should collapse (~74MB -> <25MB).
//  - flow load = one unit-stride float4; 2x waves vs round 2 for latency hiding.

#define ALPHA 0.1f

constexpr int B = 32, H = 512, W = 512;

typedef float floatx4 __attribute__((ext_vector_type(4)));

__global__ __launch_bounds__(256) void dataterm_kernel(
    const float* __restrict__ I1,
    const float* __restrict__ I2,
    const float* __restrict__ flow,
    float* __restrict__ out)
{
    // One block = one image row (256 threads x 2px = 512 = W).
    int hb = blockIdx.x;            // b*H + h  (wave-uniform)
    int h  = hb & (H - 1);
    int b  = hb >> 9;               // hb / H
    int w2 = threadIdx.x * 2;

    const float* I1b = I1 + (size_t)b * (H * W);
    // Block-uniform 3x3 corner patch (all bilinear corners live here) -> s_loads.
    float S00 = I1b[0],     S01 = I1b[1],         S02 = I1b[2];
    float S10 = I1b[W],     S11 = I1b[W + 1],     S12 = I1b[W + 2];
    float S20 = I1b[2 * W], S21 = I1b[2 * W + 1], S22 = I1b[2 * W + 2];

    size_t rowoff = (size_t)hb * W + w2;

    float2 i1v = *(const float2*)(I1 + rowoff);          // I1[w], I1[w+1]
    float2 i2v = *(const float2*)(I2 + rowoff);
    bool has_dn = (h < H - 1);
    float2 dn = make_float2(0.f, 0.f);
    if (has_dn) dn = *(const float2*)(I1 + rowoff + W);
    float i1r2 = (w2 + 2 < W) ? I1[rowoff + 2] : 0.0f;   // right neighbor

    float4 f = *(const float4*)(flow + 2 * rowoff);      // u0 v0 u1 v1 (unit stride)

    float uarr[2] = { f.x, f.z };
    float varr[2] = { f.y, f.w };
    float i1a[3]  = { i1v.x, i1v.y, i1r2 };
    float i1d[2]  = { dn.x, dn.y };
    float i2a[2]  = { i2v.x, i2v.y };

    const float sx = 2.0f / (W - 1.0f);
    const float sy = 2.0f / (H - 1.0f);

    float on[4];
#pragma unroll
    for (int j = 0; j < 2; ++j) {
        int w = w2 + j;
        float u = uarr[j], v = varr[j];
        float x = ((float)w + 0.5f * u) * sx - 1.0f;
        float y = ((float)h + 0.5f * v) * sy - 1.0f;
        float x0f = floorf(x), y0f = floorf(y);
        float x1f = x0f + 1.0f, y1f = y0f + 1.0f;
        x0f = fminf(fmaxf(x0f, 0.0f), W - 1.0f);
        x1f = fminf(fmaxf(x1f, 0.0f), W - 1.0f);
        y0f = fminf(fmaxf(y0f, 0.0f), H - 1.0f);
        y1f = fminf(fmaxf(y1f, 0.0f), H - 1.0f);
        int x0i = (int)x0f, x1i = (int)x1f;   // in {0,1} / {0,1,2}
        int y0i = (int)y0f, y1i = (int)y1f;

        // Select corner values from the preloaded 3x3 patch (pure VALU).
        float r0 = (x0i == 0) ? S00 : S01;
        float r1 = (x0i == 0) ? S10 : S11;
        float r2 = (x0i == 0) ? S20 : S21;
        float q0 = (x1i == 0) ? S00 : ((x1i == 1) ? S01 : S02);
        float q1 = (x1i == 0) ? S10 : ((x1i == 1) ? S11 : S12);
        float q2 = (x1i == 0) ? S20 : ((x1i == 1) ? S21 : S22);
        float Ia  = (y0i == 0) ? r0 : r1;
        float Ibv = (y1i == 0) ? r0 : ((y1i == 1) ? r1 : r2);
        float Ic  = (y0i == 0) ? q0 : q1;
        float Id  = (y1i == 0) ? q0 : ((y1i == 1) ? q1 : q2);

        float wa = (x1f - x) * (y1f - y);
        float wb = (x1f - x) * (y - y0f);
        float wc = (x - x0f) * (y1f - y);
        float wd = (x - x0f) * (y - y0f);
        float warped = wa * Ia + wb * Ibv + wc * Ic + wd * Id;
        float dt = warped - i2a[j];
        float gdy = has_dn ? (i1d[j] - i1a[j]) : 0.0f;          // row diff -> u
        float gdx = (w < W - 1) ? (i1a[j + 1] - i1a[j]) : 0.0f; // col diff -> v
        on[2 * j]     = u - ALPHA * dt * gdy;
        on[2 * j + 1] = v - ALPHA * dt * gdx;
    }

    floatx4 o = { on[0], on[1], on[2], on[3] };
    __builtin_nontemporal_store(o, (floatx4*)(out + 2 * rowoff));
}

extern "C" void kernel_launch(void* const* d_in, const int* in_sizes, int n_in,
                              void* d_out, int out_size, void* d_ws, size_t ws_size,
                              hipStream_t stream) {
    const float* I1   = (const float*)d_in[0];
    const float* I2   = (const float*)d_in[1];
    const float* flow = (const float*)d_in[2];
    float* out = (float*)d_out;

    int grid = B * H;               // 16384 blocks, one row each
    dataterm_kernel<<<grid, 256, 0, stream>>>(I1, I2, flow, out);
}